// Round 8
// baseline (16890.378 us; speedup 1.0000x reference)
//
#include <hip/hip_runtime.h>
#include <hip/hip_fp16.h>
#include <cmath>

// ---------------------------------------------------------------------------
// LMU fused recurrence.  One 128x1536 @ 1536x1536 GEMM per step (tanh on
// first 1024 cols, linear on last 512), x-dependent rank-1 bias.
// r8: per-step kernel launches (784 graph nodes) replace the persistent
// kernel + custom barrier.  Evidence r5-r7: no software barrier variant beats
// ~17us/step (LLC notification chain + s_sleep DPM downclock); the CP's
// inter-dispatch release/acquire is the HW-native version of the same sync.
// Step kernel: no LDS, no syncthreads, no atomics.  Weights stay in
// per-lane-fragment order in device globals; B-fragments load directly
// global->VGPR and stay L2-resident per XCD (g=bid&1 parity keeps each
// XCD serving one batch group: 2.3 MB weights + 393 KB state per L2).
// Precision (verified r3-r7, absmax 4.9e-4): f16 hi/lo for weights AND state
// (lo planes x2048), fp32 MFMA accumulate, 3 products:
//   Ah*Wh + (Al'*Wh + Ah*Wl')/2048  -> ~2^-22 effective.
// ---------------------------------------------------------------------------

typedef _Float16 half8 __attribute__((ext_vector_type(8)));
typedef float floatx4 __attribute__((ext_vector_type(4)));

#define NSTATE   1536
#define BATCH    128
#define TSTEPS   784
#define KTILES   48                 // 1536 / 32
#define WPW      24576              // weight elems per 16-col slice (16*1536)
#define LO_SCALE 2048.0f
#define LO_INV   (1.0f / 2048.0f)

// All scratch in device globals: no dependence on ws_size, no hipMalloc.
__device__ __align__(16) _Float16 g_Whi[96 * WPW];
__device__ __align__(16) _Float16 g_Wlo[96 * WPW];
__device__ float    g_wb[NSTATE];
__device__ float    g_WmA[1024 * 512];
__device__ float    g_WmB[1024];
__device__ __align__(16) _Float16 g_Shi[2 * BATCH * NSTATE];
__device__ __align__(16) _Float16 g_Slo[2 * BATCH * NSTATE];

// W_mB[i] = sum_c W_m[i,c] * BT[c]   (one wave per row, shuffle reduce)
__global__ void prep_wmb(const float* __restrict__ Wm, const float* __restrict__ BT) {
    int row  = blockIdx.x * 4 + (threadIdx.x >> 6);
    int lane = threadIdx.x & 63;
    float s = 0.f;
    for (int c = lane; c < 512; c += 64) s += Wm[row * 512 + c] * BT[c];
    for (int o = 32; o; o >>= 1) s += __shfl_down(s, o);
    if (lane == 0) g_WmB[row] = s;
}

// W_mA = W_m @ (I + AT) : tiled 32x32, fp32
__global__ void prep_wma(const float* __restrict__ Wm, const float* __restrict__ AT) {
    __shared__ float As[32][33], Bs[32][33];
    int d0 = blockIdx.x * 32, i0 = blockIdx.y * 32;
    int tx = threadIdx.x & 31, ty = threadIdx.x >> 5;   // ty in 0..7
    float acc[4];
#pragma unroll
    for (int r = 0; r < 4; ++r) acc[r] = Wm[(i0 + ty + 8 * r) * 512 + d0 + tx];
    for (int c0 = 0; c0 < 512; c0 += 32) {
#pragma unroll
        for (int r = 0; r < 4; ++r) {
            As[ty + 8 * r][tx] = Wm[(i0 + ty + 8 * r) * 512 + c0 + tx];
            Bs[ty + 8 * r][tx] = AT[(c0 + ty + 8 * r) * 512 + d0 + tx];
        }
        __syncthreads();
#pragma unroll
        for (int c = 0; c < 32; ++c)
#pragma unroll
            for (int r = 0; r < 4; ++r) acc[r] += As[ty + 8 * r][c] * Bs[c][tx];
        __syncthreads();
    }
#pragma unroll
    for (int r = 0; r < 4; ++r) g_WmA[(i0 + ty + 8 * r) * 512 + d0 + tx] = acc[r];
}

// Build W_full in MFMA-B-fragment-swizzled order, split f16 hi/lo (lo x2048).
// swizzled index s = ((p*48 + kt)*64 + lane)*8 + j
//   n = p*16 + (lane&15),  k = kt*32 + ((lane>>4)&3)*8 + j
__global__ void prep_wfull(const float* __restrict__ Wh, const float* __restrict__ AT,
                           const float* __restrict__ BT, const float* __restrict__ eh,
                           const float* __restrict__ em, const float* __restrict__ ex,
                           const float* __restrict__ Wx) {
    int s = blockIdx.x * 256 + threadIdx.x;     // [0, 96*48*64*8) exactly
    int j8 = s & 7;
    int t = s >> 3;
    int lane = t & 63;
    t >>= 6;
    int kt = t % 48;
    int p = t / 48;
    int n = p * 16 + (lane & 15);
    int k = kt * 32 + ((lane >> 4) & 3) * 8 + j8;

    float w;
    if (n < 1024) {
        if (k < 1024) w = Wh[n * 1024 + k] + g_WmB[n] * eh[k];
        else          w = g_WmA[n * 512 + (k - 1024)] + g_WmB[n] * em[k - 1024];
    } else {
        int c = n - 1024;
        if (k < 1024) w = BT[c] * eh[k];
        else {
            int d = k - 1024;
            w = ((c == d) ? 1.f : 0.f) + AT[c * 512 + d] + BT[c] * em[d];
        }
    }
    _Float16 hi = (_Float16)w;
    g_Whi[s] = hi;
    g_Wlo[s] = (_Float16)((w - (float)hi) * LO_SCALE);

    if (s < NSTATE) {
        float b = (s < 1024) ? (Wx[s] + ex[0] * g_WmB[s]) : (BT[s - 1024] * ex[0]);
        g_wb[s] = b;
    }
    if (s < 2 * BATCH * NSTATE) { g_Shi[s] = (_Float16)0.f; g_Slo[s] = (_Float16)0.f; }
}

// One recurrence step.  192 WGs x 256 threads.  g = bid&1 (batch group),
// p = bid>>1 (column tile): CP round-robins bids over XCDs, so each XCD
// serves one group's state + a fixed 2.3 MB weight set, L2-warm for all 784
// dispatches.  No LDS, no barriers — sync is the dispatch boundary.
__launch_bounds__(256, 1)
__global__ void lmu_step(const float* __restrict__ inputs, int t) {
    const int bid = blockIdx.x;
    const int g = bid & 1;
    const int p = bid >> 1;                     // column tile [0,96)
    const int tid = threadIdx.x;
    const int lane = tid & 63, wv = tid >> 6;
    const int quad = lane >> 4, l16 = lane & 15;
    const int b0 = g * 64 + wv * 16;            // this wave's 16-row block
    const int n = p * 16 + l16;                 // this lane's output column
    const int rowA = b0 + l16;                  // A-fragment row for this lane
    const int buf = t & 1, nbuf = buf ^ 1;

    const half8* wh = (const half8*)g_Whi + (size_t)p * KTILES * 64 + lane;
    const half8* wl = (const half8*)g_Wlo + (size_t)p * KTILES * 64 + lane;
    const _Float16* shr = g_Shi + buf * BATCH * NSTATE + rowA * NSTATE + quad * 8;
    const _Float16* slr = g_Slo + buf * BATCH * NSTATE + rowA * NSTATE + quad * 8;

    const float wbv = g_wb[n];
    const bool do_tanh = (p < 64);
    const float* xt = inputs + t * BATCH;
    float xv[4];
#pragma unroll
    for (int r = 0; r < 4; ++r) xv[r] = xt[b0 + quad * 4 + r];

    floatx4 aA[2], aB[2], aC[2];
#pragma unroll
    for (int q = 0; q < 2; ++q) { aA[q] = (floatx4)0.f; aB[q] = (floatx4)0.f; aC[q] = (floatx4)0.f; }

#pragma unroll
    for (int kt = 0; kt < KTILES; ++kt) {
        half8 ah = *(const half8*)(shr + kt * 32);
        half8 al = *(const half8*)(slr + kt * 32);
        half8 bh = wh[kt * 64];
        half8 bl = wl[kt * 64];
        aA[kt & 1] = __builtin_amdgcn_mfma_f32_16x16x32_f16(ah, bh, aA[kt & 1], 0, 0, 0);
        aB[kt & 1] = __builtin_amdgcn_mfma_f32_16x16x32_f16(al, bh, aB[kt & 1], 0, 0, 0);
        aC[kt & 1] = __builtin_amdgcn_mfma_f32_16x16x32_f16(ah, bl, aC[kt & 1], 0, 0, 0);
    }

    _Float16* dh = g_Shi + nbuf * BATCH * NSTATE;
    _Float16* dl = g_Slo + nbuf * BATCH * NSTATE;
#pragma unroll
    for (int r = 0; r < 4; ++r) {
        int b = b0 + quad * 4 + r;
        float v = (aA[0][r] + aA[1][r])
                + ((aB[0][r] + aB[1][r]) + (aC[0][r] + aC[1][r])) * LO_INV;
        v += xv[r] * wbv;
        if (do_tanh) v = tanhf(v);
        _Float16 hi = (_Float16)v;
        dh[b * NSTATE + n] = hi;
        dl[b * NSTATE + n] = (_Float16)((v - (float)hi) * LO_SCALE);
    }
}

// logits + softmax: one WG per batch row.  Final state is in plane 0
// (784 steps, even -> buf back to 0).
__global__ void lmu_out(const float* __restrict__ Wd, const float* __restrict__ bd,
                        float* __restrict__ out) {
    __shared__ float red[272];
    int b = blockIdx.x;
    const _Float16* sh = g_Shi + b * NSTATE;
    const _Float16* sl = g_Slo + b * NSTATE;
    int tid = threadIdx.x;
    int c = tid & 15, chunk = tid >> 4;          // 16 chunks x 64 elems = 1024
    float part = 0.f;
    if (c < 10) {
        for (int i = chunk * 64; i < chunk * 64 + 64; ++i)
            part += ((float)sh[i] + (float)sl[i] * LO_INV) * Wd[c * 1024 + i];
    }
    red[chunk * 16 + c] = part;
    __syncthreads();
    if (tid < 10) {
        float lg = bd[tid];
        for (int q = 0; q < 16; ++q) lg += red[q * 16 + tid];
        red[256 + tid] = lg;
    }
    __syncthreads();
    if (tid < 10) {
        float mx = red[256];
        for (int q = 1; q < 10; ++q) mx = fmaxf(mx, red[256 + q]);
        float sm = 0.f;
        for (int q = 0; q < 10; ++q) sm += expf(red[256 + q] - mx);
        out[b * 10 + tid] = expf(red[256 + tid] - mx) / sm;
    }
}

extern "C" void kernel_launch(void* const* d_in, const int* in_sizes, int n_in,
                              void* d_out, int out_size, void* d_ws, size_t ws_size,
                              hipStream_t stream) {
    const float* inputs = (const float*)d_in[0];
    const float* e_x    = (const float*)d_in[1];
    const float* e_h    = (const float*)d_in[2];
    const float* e_m    = (const float*)d_in[3];
    const float* W_x    = (const float*)d_in[4];
    const float* W_h    = (const float*)d_in[5];
    const float* W_m    = (const float*)d_in[6];
    const float* AT     = (const float*)d_in[7];
    const float* BT     = (const float*)d_in[8];
    const float* W_d    = (const float*)d_in[9];
    const float* b_d    = (const float*)d_in[10];
    (void)d_ws; (void)ws_size; (void)in_sizes; (void)n_in;

    prep_wmb<<<256, 256, 0, stream>>>(W_m, BT);
    prep_wma<<<dim3(16, 32), 256, 0, stream>>>(W_m, AT);
    prep_wfull<<<9216, 256, 0, stream>>>(W_h, AT, BT, e_h, e_m, e_x, W_x);

    for (int t = 0; t < TSTEPS; ++t)
        lmu_step<<<192, 256, 0, stream>>>(inputs, t);

    lmu_out<<<128, 256, 0, stream>>>(W_d, b_d, (float*)d_out);
}

// Round 9
// 11179.852 us; speedup vs baseline: 1.5108x; 1.5108x over previous
//
#include <hip/hip_runtime.h>
#include <hip/hip_fp16.h>
#include <cmath>

// ---------------------------------------------------------------------------
// LMU fused recurrence.  One 128x1536 @ 1536x1536 GEMM per step (tanh on
// first 1024 cols, linear on last 512), x-dependent rank-1 bias.
// r9: ISLAND decomposition.  r5-r8 showed every chip-wide step-sync
// (software barrier OR dispatch boundary) floors at ~17-21us/step.  Batch
// rows are independent -> 8 islands x 16 rows, 32 WGs each (256 WGs, 1/CU,
// LDS-limited).  Each island syncs only its 32 WGs on its own LLC line.
// State loads+stores are volatile (LLC-coherent) -> ZERO cache-maintenance
// ops per step (weights/x immutable; no L1/L2 inv, no wbl2, ever).
// W_hi slice (48 cols, 147456 B) in LDS; W_lo streamed (L2-cached);
// 4 waves/WG split K (12 ktiles each), partials reduced via 12 KB LDS.
// Precision: EXACT r3-r7 verified scheme (absmax 4.9e-4): f16 hi/lo state
// and weights (lo x2048), fp32 MFMA accumulate, 3 products.
// ---------------------------------------------------------------------------

typedef _Float16 half8 __attribute__((ext_vector_type(8)));
typedef float floatx4 __attribute__((ext_vector_type(4)));

#define NSTATE   1536
#define BATCH    128
#define TSTEPS   784
#define KTILES   48
#define ISL_WGS  32                  // WGs per island
#define SLICE_H8 9216                // half8 per 48-col weight slice (48*3*64)
#define LO_SCALE 2048.0f
#define LO_INV   (1.0f / 2048.0f)

__device__ __align__(16) _Float16 g_Whi[NSTATE * NSTATE];
__device__ __align__(16) _Float16 g_Wlo[NSTATE * NSTATE];
__device__ float    g_wb[NSTATE];
__device__ float    g_WmA[1024 * 512];
__device__ float    g_WmB[1024];
__device__ __align__(16) _Float16 g_Shi[2 * BATCH * NSTATE];
__device__ __align__(16) _Float16 g_Slo[2 * BATCH * NSTATE];
__device__ unsigned g_bar[512];      // 8 islands x 64-word (256B) sectors

// W_mB[i] = sum_c W_m[i,c] * BT[c]
__global__ void prep_wmb(const float* __restrict__ Wm, const float* __restrict__ BT) {
    int row  = blockIdx.x * 4 + (threadIdx.x >> 6);
    int lane = threadIdx.x & 63;
    float s = 0.f;
    for (int c = lane; c < 512; c += 64) s += Wm[row * 512 + c] * BT[c];
    for (int o = 32; o; o >>= 1) s += __shfl_down(s, o);
    if (lane == 0) g_WmB[row] = s;
}

// W_mA = W_m @ (I + AT)
__global__ void prep_wma(const float* __restrict__ Wm, const float* __restrict__ AT) {
    __shared__ float As[32][33], Bs[32][33];
    int d0 = blockIdx.x * 32, i0 = blockIdx.y * 32;
    int tx = threadIdx.x & 31, ty = threadIdx.x >> 5;
    float acc[4];
#pragma unroll
    for (int r = 0; r < 4; ++r) acc[r] = Wm[(i0 + ty + 8 * r) * 512 + d0 + tx];
    for (int c0 = 0; c0 < 512; c0 += 32) {
#pragma unroll
        for (int r = 0; r < 4; ++r) {
            As[ty + 8 * r][tx] = Wm[(i0 + ty + 8 * r) * 512 + c0 + tx];
            Bs[ty + 8 * r][tx] = AT[(c0 + ty + 8 * r) * 512 + d0 + tx];
        }
        __syncthreads();
#pragma unroll
        for (int c = 0; c < 32; ++c)
#pragma unroll
            for (int r = 0; r < 4; ++r) acc[r] += As[ty + 8 * r][c] * Bs[c][tx];
        __syncthreads();
    }
#pragma unroll
    for (int r = 0; r < 4; ++r) g_WmA[(i0 + ty + 8 * r) * 512 + d0 + tx] = acc[r];
}

// Build W_full, f16 hi/lo (lo x2048), in slice-major fragment order:
// storage s = (((sl*48 + kt)*3 + nt)*64 + lane)*8 + j
//   n = sl*48 + nt*16 + (lane&15),  k = kt*32 + ((lane>>4)&3)*8 + j
__global__ void prep_wfull(const float* __restrict__ Wh, const float* __restrict__ AT,
                           const float* __restrict__ BT, const float* __restrict__ eh,
                           const float* __restrict__ em, const float* __restrict__ ex,
                           const float* __restrict__ Wx) {
    int s = blockIdx.x * 256 + threadIdx.x;     // [0, 1536*1536)
    int j8 = s & 7;
    int u = s >> 3;
    int lane = u & 63;
    u >>= 6;                                    // [0, 4608)
    int nt = u % 3; u /= 3;
    int kt = u % 48;
    int sl = u / 48;
    int n = sl * 48 + nt * 16 + (lane & 15);
    int k = kt * 32 + ((lane >> 4) & 3) * 8 + j8;

    float w;
    if (n < 1024) {
        if (k < 1024) w = Wh[n * 1024 + k] + g_WmB[n] * eh[k];
        else          w = g_WmA[n * 512 + (k - 1024)] + g_WmB[n] * em[k - 1024];
    } else {
        int c = n - 1024;
        if (k < 1024) w = BT[c] * eh[k];
        else {
            int d = k - 1024;
            w = ((c == d) ? 1.f : 0.f) + AT[c * 512 + d] + BT[c] * em[d];
        }
    }
    _Float16 hi = (_Float16)w;
    g_Whi[s] = hi;
    g_Wlo[s] = (_Float16)((w - (float)hi) * LO_SCALE);

    if (s < NSTATE) {
        float b = (s < 1024) ? (Wx[s] + ex[0] * g_WmB[s]) : (BT[s - 1024] * ex[0]);
        g_wb[s] = b;
    }
    if (s < 2 * BATCH * NSTATE) { g_Shi[s] = (_Float16)0.f; g_Slo[s] = (_Float16)0.f; }
    if (s < 512) g_bar[s] = 0u;
}

__launch_bounds__(256, 1)
__global__ void lmu_persist(const float* __restrict__ inputs) {
    __shared__ half8  lwh[SLICE_H8];            // 147456 B: W_hi slice
    __shared__ float4 red[4 * 3 * 64];          // 12288 B: K-split partials

    const int tid = threadIdx.x;
    const int bid = blockIdx.x;
    const int isl = bid >> 5;                   // island [0,8): batch rows isl*16..+16
    const int sl  = bid & 31;                   // column slice [0,32): cols sl*48..+48

    // stage W_hi slice -> LDS
    {
        const half8* src = (const half8*)g_Whi + (size_t)sl * SLICE_H8;
        for (int i = tid; i < SLICE_H8; i += 256) lwh[i] = src[i];
    }

    const int lane = tid & 63, wv = tid >> 6;
    const int quad = lane >> 4, l16 = lane & 15;
    const int kt0 = wv * 12;                    // this wave's K range
    const int rowA = isl * 16 + l16;            // A-frag batch row
    const half8* wlo = (const half8*)g_Wlo + (size_t)sl * SLICE_H8;
    unsigned* cnt = g_bar + isl * 64;           // island arrival counter (LLC)

    // epilogue constants (wave wv<3 handles nt=wv)
    const int ncol = sl * 48 + wv * 16 + l16;
    const float wbv = (wv < 3) ? g_wb[ncol] : 0.f;
    const bool do_tanh = (sl * 48 + wv * 16) < 1024;

    __syncthreads();

    int buf = 0;
    for (int t = 0; t < TSTEPS; ++t) {
        const volatile _Float16* shr =
            g_Shi + buf * BATCH * NSTATE + rowA * NSTATE + quad * 8;
        const volatile _Float16* slr =
            g_Slo + buf * BATCH * NSTATE + rowA * NSTATE + quad * 8;

        floatx4 aA[3], aB[3], aC[3];
#pragma unroll
        for (int q = 0; q < 3; ++q) { aA[q] = (floatx4)0.f; aB[q] = (floatx4)0.f; aC[q] = (floatx4)0.f; }

#pragma unroll
        for (int ki = 0; ki < 12; ++ki) {
            const int kt = kt0 + ki;
            half8 ah = *(const volatile half8*)(shr + kt * 32);
            half8 al = *(const volatile half8*)(slr + kt * 32);
#pragma unroll
            for (int nt = 0; nt < 3; ++nt) {
                half8 bh = lwh[(kt * 3 + nt) * 64 + lane];
                half8 bl = wlo[(kt * 3 + nt) * 64 + lane];
                aA[nt] = __builtin_amdgcn_mfma_f32_16x16x32_f16(ah, bh, aA[nt], 0, 0, 0);
                aB[nt] = __builtin_amdgcn_mfma_f32_16x16x32_f16(al, bh, aB[nt], 0, 0, 0);
                aC[nt] = __builtin_amdgcn_mfma_f32_16x16x32_f16(ah, bl, aC[nt], 0, 0, 0);
            }
        }

        // K-split partials -> LDS
#pragma unroll
        for (int nt = 0; nt < 3; ++nt) {
            floatx4 P = aA[nt] + (aB[nt] + aC[nt]) * LO_INV;
            red[(wv * 3 + nt) * 64 + lane] = float4{P[0], P[1], P[2], P[3]};
        }
        __syncthreads();

        // waves 0-2: reduce + bias + activation + hi/lo split + volatile store
        const int nbuf = buf ^ 1;
        if (wv < 3) {
            float4 v0 = red[(0 * 3 + wv) * 64 + lane];
            float4 v1 = red[(1 * 3 + wv) * 64 + lane];
            float4 v2 = red[(2 * 3 + wv) * 64 + lane];
            float4 v3 = red[(3 * 3 + wv) * 64 + lane];
            float vr[4] = {v0.x + v1.x + v2.x + v3.x, v0.y + v1.y + v2.y + v3.y,
                           v0.z + v1.z + v2.z + v3.z, v0.w + v1.w + v2.w + v3.w};
            volatile _Float16* dh = g_Shi + nbuf * BATCH * NSTATE;
            volatile _Float16* dl = g_Slo + nbuf * BATCH * NSTATE;
            const float* xt = inputs + t * BATCH + isl * 16 + quad * 4;
#pragma unroll
            for (int r = 0; r < 4; ++r) {
                int b = isl * 16 + quad * 4 + r;
                float v = vr[r] + xt[r] * wbv;
                if (do_tanh) v = tanhf(v);
                _Float16 hi = (_Float16)v;
                dh[b * NSTATE + ncol] = hi;
                dl[b * NSTATE + ncol] = (_Float16)((v - (float)hi) * LO_SCALE);
            }
        }

        // drain stores (syncthreads emits vmcnt(0) per wave), then island barrier
        __builtin_amdgcn_fence(__ATOMIC_RELEASE, "workgroup");
        __syncthreads();
        if (tid == 0) {
            __hip_atomic_fetch_add(cnt, 1u, __ATOMIC_RELAXED,
                                   __HIP_MEMORY_SCOPE_AGENT);
            const unsigned target = (unsigned)ISL_WGS * (unsigned)(t + 1);
            int spin = 0;
            while (__hip_atomic_load(cnt, __ATOMIC_RELAXED,
                                     __HIP_MEMORY_SCOPE_AGENT) < target) {
                __builtin_amdgcn_s_sleep(1);
                if (++spin > (1 << 17)) break;  // deadman: no hang
            }
        }
        __syncthreads();
        __builtin_amdgcn_fence(__ATOMIC_ACQUIRE, "workgroup");
        buf = nbuf;
    }
}

// logits + softmax: one WG per batch row (final state in plane 0: 784 even).
__global__ void lmu_out(const float* __restrict__ Wd, const float* __restrict__ bd,
                        float* __restrict__ out) {
    __shared__ float red[272];
    int b = blockIdx.x;
    const _Float16* sh = g_Shi + b * NSTATE;
    const _Float16* sl = g_Slo + b * NSTATE;
    int tid = threadIdx.x;
    int c = tid & 15, chunk = tid >> 4;
    float part = 0.f;
    if (c < 10) {
        for (int i = chunk * 64; i < chunk * 64 + 64; ++i)
            part += ((float)sh[i] + (float)sl[i] * LO_INV) * Wd[c * 1024 + i];
    }
    red[chunk * 16 + c] = part;
    __syncthreads();
    if (tid < 10) {
        float lg = bd[tid];
        for (int q = 0; q < 16; ++q) lg += red[q * 16 + tid];
        red[256 + tid] = lg;
    }
    __syncthreads();
    if (tid < 10) {
        float mx = red[256];
        for (int q = 1; q < 10; ++q) mx = fmaxf(mx, red[256 + q]);
        float sm = 0.f;
        for (int q = 0; q < 10; ++q) sm += expf(red[256 + q] - mx);
        out[b * 10 + tid] = expf(red[256 + tid] - mx) / sm;
    }
}

extern "C" void kernel_launch(void* const* d_in, const int* in_sizes, int n_in,
                              void* d_out, int out_size, void* d_ws, size_t ws_size,
                              hipStream_t stream) {
    const float* inputs = (const float*)d_in[0];
    const float* e_x    = (const float*)d_in[1];
    const float* e_h    = (const float*)d_in[2];
    const float* e_m    = (const float*)d_in[3];
    const float* W_x    = (const float*)d_in[4];
    const float* W_h    = (const float*)d_in[5];
    const float* W_m    = (const float*)d_in[6];
    const float* AT     = (const float*)d_in[7];
    const float* BT     = (const float*)d_in[8];
    const float* W_d    = (const float*)d_in[9];
    const float* b_d    = (const float*)d_in[10];
    (void)d_ws; (void)ws_size; (void)in_sizes; (void)n_in;

    prep_wmb<<<256, 256, 0, stream>>>(W_m, BT);
    prep_wma<<<dim3(16, 32), 256, 0, stream>>>(W_m, AT);
    prep_wfull<<<9216, 256, 0, stream>>>(W_h, AT, BT, e_h, e_m, e_x, W_x);

    lmu_persist<<<256, 256, 0, stream>>>(inputs);

    lmu_out<<<128, 256, 0, stream>>>(W_d, b_d, (float*)d_out);
}

// Round 10
// 9076.760 us; speedup vs baseline: 1.8608x; 1.2317x over previous
//
#include <hip/hip_runtime.h>
#include <hip/hip_fp16.h>
#include <cmath>

// ---------------------------------------------------------------------------
// LMU fused recurrence.  One 128x1536 @ 1536x1536 GEMM per step (tanh on
// first 1024 cols, linear on last 512), x-dependent rank-1 bias.
// r10: XCD-LOCAL islands.  r9 spread each island over all 8 XCDs, forcing
// volatile/LLC state traffic (25 MB/step at ~2.3 TB/s = the 14us/step).
// Now island = physical XCD (s_getreg HW_REG_XCC_ID + runtime rank
// registration; 256 WGs at 1 WG/CU fill 8x32 CUs exactly).  Producers and
// consumers of a 16-row block share one L2: state stores are PLAIN
// (write-through to local L2), state loads are PLAIN L2-cached, and the only
// per-step cache op is a CU-local L1 buffer_inv.  Zero LLC data traffic.
// Island barrier: unchanged r9 agent-scope LLC line (one variable per round).
// W_hi slice (48 cols, 147 KB) in LDS; W_lo streamed from L2; 4 waves split
// K (12 ktiles each), partials reduced via 12 KB LDS.
// Precision: EXACT r3-r9 verified scheme (absmax 4.9e-4): f16 hi/lo state
// and weights (lo x2048), fp32 MFMA accumulate, 3 products.
// ---------------------------------------------------------------------------

typedef _Float16 half8 __attribute__((ext_vector_type(8)));
typedef float floatx4 __attribute__((ext_vector_type(4)));

#define NSTATE   1536
#define BATCH    128
#define TSTEPS   784
#define KTILES   48
#define ISL_WGS  32                  // WGs per island (= CUs per XCD)
#define SLICE_H8 9216                // half8 per 48-col weight slice (48*3*64)
#define LO_SCALE 2048.0f
#define LO_INV   (1.0f / 2048.0f)

__device__ __align__(16) _Float16 g_Whi[NSTATE * NSTATE];
__device__ __align__(16) _Float16 g_Wlo[NSTATE * NSTATE];
__device__ float    g_wb[NSTATE];
__device__ float    g_WmA[1024 * 512];
__device__ float    g_WmB[1024];
__device__ __align__(16) _Float16 g_Shi[2 * BATCH * NSTATE];
__device__ __align__(16) _Float16 g_Slo[2 * BATCH * NSTATE];
// [xcd*64]: island arrival counters; [512 + xcd*64]: registration counters
__device__ unsigned g_bar[1024];

// W_mB[i] = sum_c W_m[i,c] * BT[c]
__global__ void prep_wmb(const float* __restrict__ Wm, const float* __restrict__ BT) {
    int row  = blockIdx.x * 4 + (threadIdx.x >> 6);
    int lane = threadIdx.x & 63;
    float s = 0.f;
    for (int c = lane; c < 512; c += 64) s += Wm[row * 512 + c] * BT[c];
    for (int o = 32; o; o >>= 1) s += __shfl_down(s, o);
    if (lane == 0) g_WmB[row] = s;
}

// W_mA = W_m @ (I + AT)
__global__ void prep_wma(const float* __restrict__ Wm, const float* __restrict__ AT) {
    __shared__ float As[32][33], Bs[32][33];
    int d0 = blockIdx.x * 32, i0 = blockIdx.y * 32;
    int tx = threadIdx.x & 31, ty = threadIdx.x >> 5;
    float acc[4];
#pragma unroll
    for (int r = 0; r < 4; ++r) acc[r] = Wm[(i0 + ty + 8 * r) * 512 + d0 + tx];
    for (int c0 = 0; c0 < 512; c0 += 32) {
#pragma unroll
        for (int r = 0; r < 4; ++r) {
            As[ty + 8 * r][tx] = Wm[(i0 + ty + 8 * r) * 512 + c0 + tx];
            Bs[ty + 8 * r][tx] = AT[(c0 + ty + 8 * r) * 512 + d0 + tx];
        }
        __syncthreads();
#pragma unroll
        for (int c = 0; c < 32; ++c)
#pragma unroll
            for (int r = 0; r < 4; ++r) acc[r] += As[ty + 8 * r][c] * Bs[c][tx];
        __syncthreads();
    }
#pragma unroll
    for (int r = 0; r < 4; ++r) g_WmA[(i0 + ty + 8 * r) * 512 + d0 + tx] = acc[r];
}

// Build W_full, f16 hi/lo (lo x2048), in slice-major fragment order:
// storage s = (((sl*48 + kt)*3 + nt)*64 + lane)*8 + j
//   n = sl*48 + nt*16 + (lane&15),  k = kt*32 + ((lane>>4)&3)*8 + j
__global__ void prep_wfull(const float* __restrict__ Wh, const float* __restrict__ AT,
                           const float* __restrict__ BT, const float* __restrict__ eh,
                           const float* __restrict__ em, const float* __restrict__ ex,
                           const float* __restrict__ Wx) {
    int s = blockIdx.x * 256 + threadIdx.x;     // [0, 1536*1536)
    int j8 = s & 7;
    int u = s >> 3;
    int lane = u & 63;
    u >>= 6;                                    // [0, 4608)
    int nt = u % 3; u /= 3;
    int kt = u % 48;
    int sl = u / 48;
    int n = sl * 48 + nt * 16 + (lane & 15);
    int k = kt * 32 + ((lane >> 4) & 3) * 8 + j8;

    float w;
    if (n < 1024) {
        if (k < 1024) w = Wh[n * 1024 + k] + g_WmB[n] * eh[k];
        else          w = g_WmA[n * 512 + (k - 1024)] + g_WmB[n] * em[k - 1024];
    } else {
        int c = n - 1024;
        if (k < 1024) w = BT[c] * eh[k];
        else {
            int d = k - 1024;
            w = ((c == d) ? 1.f : 0.f) + AT[c * 512 + d] + BT[c] * em[d];
        }
    }
    _Float16 hi = (_Float16)w;
    g_Whi[s] = hi;
    g_Wlo[s] = (_Float16)((w - (float)hi) * LO_SCALE);

    if (s < NSTATE) {
        float b = (s < 1024) ? (Wx[s] + ex[0] * g_WmB[s]) : (BT[s - 1024] * ex[0]);
        g_wb[s] = b;
    }
    if (s < 2 * BATCH * NSTATE) { g_Shi[s] = (_Float16)0.f; g_Slo[s] = (_Float16)0.f; }
    if (s < 1024) g_bar[s] = 0u;
}

__launch_bounds__(256, 1)
__global__ void lmu_persist(const float* __restrict__ inputs) {
    __shared__ half8  lwh[SLICE_H8];            // 147456 B: W_hi slice
    __shared__ float4 red[4 * 3 * 64];          // 12288 B: K-split partials
    __shared__ int    s_sl;

    const int tid = threadIdx.x;

    // ---- physical XCD id + rank registration (island = XCD) ----
    unsigned xcd;
    asm volatile("s_getreg_b32 %0, hwreg(HW_REG_XCC_ID)" : "=s"(xcd));
    xcd &= 7u;
    if (tid == 0) {
        unsigned rank = __hip_atomic_fetch_add(g_bar + 512 + xcd * 64, 1u,
                                               __ATOMIC_RELAXED,
                                               __HIP_MEMORY_SCOPE_AGENT);
        s_sl = (int)(rank & 31u);               // column slice [0,32)
    }
    __syncthreads();
    const int isl = (int)xcd;                   // batch rows isl*16..+16
    const int sl  = s_sl;                       // cols sl*48..+48

    // stage W_hi slice -> LDS
    {
        const half8* src = (const half8*)g_Whi + (size_t)sl * SLICE_H8;
        for (int i = tid; i < SLICE_H8; i += 256) lwh[i] = src[i];
    }

    const int lane = tid & 63, wv = tid >> 6;
    const int quad = lane >> 4, l16 = lane & 15;
    const int kt0 = wv * 12;                    // this wave's K range
    const int rowA = isl * 16 + l16;            // A-frag batch row
    const half8* wlo = (const half8*)g_Wlo + (size_t)sl * SLICE_H8;
    unsigned* cnt = g_bar + isl * 64;           // island arrival counter (LLC)

    // epilogue constants (wave wv<3 handles nt=wv)
    const int ncol = sl * 48 + wv * 16 + l16;
    const float wbv = (wv < 3) ? g_wb[ncol] : 0.f;
    const bool do_tanh = (sl * 48 + wv * 16) < 1024;

    __syncthreads();

    int buf = 0;
    for (int t = 0; t < TSTEPS; ++t) {
        // PLAIN loads: producers share this XCD's L2 -> L2-local traffic
        const _Float16* shr =
            g_Shi + buf * BATCH * NSTATE + rowA * NSTATE + quad * 8;
        const _Float16* slr =
            g_Slo + buf * BATCH * NSTATE + rowA * NSTATE + quad * 8;

        floatx4 aA[3], aB[3], aC[3];
#pragma unroll
        for (int q = 0; q < 3; ++q) { aA[q] = (floatx4)0.f; aB[q] = (floatx4)0.f; aC[q] = (floatx4)0.f; }

#pragma unroll
        for (int ki = 0; ki < 12; ++ki) {
            const int kt = kt0 + ki;
            half8 ah = *(const half8*)(shr + kt * 32);
            half8 al = *(const half8*)(slr + kt * 32);
#pragma unroll
            for (int nt = 0; nt < 3; ++nt) {
                half8 bh = lwh[(kt * 3 + nt) * 64 + lane];
                half8 bl = wlo[(kt * 3 + nt) * 64 + lane];
                aA[nt] = __builtin_amdgcn_mfma_f32_16x16x32_f16(ah, bh, aA[nt], 0, 0, 0);
                aB[nt] = __builtin_amdgcn_mfma_f32_16x16x32_f16(al, bh, aB[nt], 0, 0, 0);
                aC[nt] = __builtin_amdgcn_mfma_f32_16x16x32_f16(ah, bl, aC[nt], 0, 0, 0);
            }
        }

        // K-split partials -> LDS
#pragma unroll
        for (int nt = 0; nt < 3; ++nt) {
            floatx4 P = aA[nt] + (aB[nt] + aC[nt]) * LO_INV;
            red[(wv * 3 + nt) * 64 + lane] = float4{P[0], P[1], P[2], P[3]};
        }
        __syncthreads();

        // waves 0-2: reduce + bias + activation + hi/lo split + PLAIN store
        // (write-through L1 lands in the local XCD L2 = island coherence point)
        const int nbuf = buf ^ 1;
        if (wv < 3) {
            float4 v0 = red[(0 * 3 + wv) * 64 + lane];
            float4 v1 = red[(1 * 3 + wv) * 64 + lane];
            float4 v2 = red[(2 * 3 + wv) * 64 + lane];
            float4 v3 = red[(3 * 3 + wv) * 64 + lane];
            float vr[4] = {v0.x + v1.x + v2.x + v3.x, v0.y + v1.y + v2.y + v3.y,
                           v0.z + v1.z + v2.z + v3.z, v0.w + v1.w + v2.w + v3.w};
            _Float16* dh = g_Shi + nbuf * BATCH * NSTATE;
            _Float16* dl = g_Slo + nbuf * BATCH * NSTATE;
            const float* xt = inputs + t * BATCH + isl * 16 + quad * 4;
#pragma unroll
            for (int r = 0; r < 4; ++r) {
                int b = isl * 16 + quad * 4 + r;
                float v = vr[r] + xt[r] * wbv;
                if (do_tanh) v = tanhf(v);
                _Float16 hi = (_Float16)v;
                dh[b * NSTATE + ncol] = hi;
                dl[b * NSTATE + ncol] = (_Float16)((v - (float)hi) * LO_SCALE);
            }
        }

        // drain stores (syncthreads emits vmcnt(0)), then island barrier (LLC)
        __builtin_amdgcn_fence(__ATOMIC_RELEASE, "workgroup");
        __syncthreads();
        if (tid == 0) {
            __hip_atomic_fetch_add(cnt, 1u, __ATOMIC_RELAXED,
                                   __HIP_MEMORY_SCOPE_AGENT);
            const unsigned target = (unsigned)ISL_WGS * (unsigned)(t + 1);
            int spin = 0;
            while (__hip_atomic_load(cnt, __ATOMIC_RELAXED,
                                     __HIP_MEMORY_SCOPE_AGENT) < target) {
                __builtin_amdgcn_s_sleep(1);
                if (++spin > (1 << 17)) break;  // deadman: no hang
            }
        }
        __syncthreads();
        // CU-local L1 invalidate only (L2 holds the island's fresh state)
        asm volatile("buffer_inv\n\ts_waitcnt vmcnt(0)" ::: "memory");
        __builtin_amdgcn_fence(__ATOMIC_ACQUIRE, "workgroup");
        buf = nbuf;
    }
}

// logits + softmax: one WG per batch row (final state in plane 0: 784 even;
// dispatch boundary flushes every XCD's L2 so state is globally visible).
__global__ void lmu_out(const float* __restrict__ Wd, const float* __restrict__ bd,
                        float* __restrict__ out) {
    __shared__ float red[272];
    int b = blockIdx.x;
    const _Float16* sh = g_Shi + b * NSTATE;
    const _Float16* sl = g_Slo + b * NSTATE;
    int tid = threadIdx.x;
    int c = tid & 15, chunk = tid >> 4;
    float part = 0.f;
    if (c < 10) {
        for (int i = chunk * 64; i < chunk * 64 + 64; ++i)
            part += ((float)sh[i] + (float)sl[i] * LO_INV) * Wd[c * 1024 + i];
    }
    red[chunk * 16 + c] = part;
    __syncthreads();
    if (tid < 10) {
        float lg = bd[tid];
        for (int q = 0; q < 16; ++q) lg += red[q * 16 + tid];
        red[256 + tid] = lg;
    }
    __syncthreads();
    if (tid < 10) {
        float mx = red[256];
        for (int q = 1; q < 10; ++q) mx = fmaxf(mx, red[256 + q]);
        float sm = 0.f;
        for (int q = 0; q < 10; ++q) sm += expf(red[256 + q] - mx);
        out[b * 10 + tid] = expf(red[256 + tid] - mx) / sm;
    }
}

extern "C" void kernel_launch(void* const* d_in, const int* in_sizes, int n_in,
                              void* d_out, int out_size, void* d_ws, size_t ws_size,
                              hipStream_t stream) {
    const float* inputs = (const float*)d_in[0];
    const float* e_x    = (const float*)d_in[1];
    const float* e_h    = (const float*)d_in[2];
    const float* e_m    = (const float*)d_in[3];
    const float* W_x    = (const float*)d_in[4];
    const float* W_h    = (const float*)d_in[5];
    const float* W_m    = (const float*)d_in[6];
    const float* AT     = (const float*)d_in[7];
    const float* BT     = (const float*)d_in[8];
    const float* W_d    = (const float*)d_in[9];
    const float* b_d    = (const float*)d_in[10];
    (void)d_ws; (void)ws_size; (void)in_sizes; (void)n_in;

    prep_wmb<<<256, 256, 0, stream>>>(W_m, BT);
    prep_wma<<<dim3(16, 32), 256, 0, stream>>>(W_m, AT);
    prep_wfull<<<9216, 256, 0, stream>>>(W_h, AT, BT, e_h, e_m, e_x, W_x);

    lmu_persist<<<256, 256, 0, stream>>>(inputs);

    lmu_out<<<128, 256, 0, stream>>>(W_d, b_d, (float*)d_out);
}

// Round 11
// 5382.413 us; speedup vs baseline: 3.1381x; 1.6864x over previous
//
#include <hip/hip_runtime.h>
#include <hip/hip_fp16.h>
#include <cmath>

// ---------------------------------------------------------------------------
// LMU fused recurrence.  One 128x1536 @ 1536x1536 GEMM per step (tanh on
// first 1024 cols, linear on last 512), x-dependent rank-1 bias.
// r11: register/stream hybrid for W_lo.  r10's counters: FETCH_SIZE 14.6 GB
// (W_lo working set 4.7 MB/XCD > 4 MB L2 -> stream thrash beyond L2 = the
// remaining 7ms).  Fix: each wave keeps its first 8 ktiles of W_lo in
// REGISTERS (24 x half8 = 96 VGPR; 132+96=228 < 256 arch ceiling -- r1's
// failed attempt was 324), loaded ONCE before the t-loop; only 4 ktiles
// stream (49 KB/WG -> 1.57 MB/XCD, L2-resident).  Everything else = r10:
// XCD-local islands (s_getreg XCC_ID + rank registration), plain L2-local
// state loads/stores, per-step CU-local L1 buffer_inv, island barrier on an
// L2-completing atomic line.
// Precision: EXACT r3-r10 verified scheme (absmax 4.9e-4): f16 hi/lo state
// and weights (lo x2048), fp32 MFMA accumulate, 3 products.
// ---------------------------------------------------------------------------

typedef _Float16 half8 __attribute__((ext_vector_type(8)));
typedef float floatx4 __attribute__((ext_vector_type(4)));

#define NSTATE   1536
#define BATCH    128
#define TSTEPS   784
#define KTILES   48
#define ISL_WGS  32                  // WGs per island (= CUs per XCD)
#define SLICE_H8 9216                // half8 per 48-col weight slice (48*3*64)
#define KREG     8                   // ktiles of W_lo held in registers/wave
#define LO_SCALE 2048.0f
#define LO_INV   (1.0f / 2048.0f)

__device__ __align__(16) _Float16 g_Whi[NSTATE * NSTATE];
__device__ __align__(16) _Float16 g_Wlo[NSTATE * NSTATE];
__device__ float    g_wb[NSTATE];
__device__ float    g_WmA[1024 * 512];
__device__ float    g_WmB[1024];
__device__ __align__(16) _Float16 g_Shi[2 * BATCH * NSTATE];
__device__ __align__(16) _Float16 g_Slo[2 * BATCH * NSTATE];
// [xcd*64]: island arrival counters; [512 + xcd*64]: registration counters
__device__ unsigned g_bar[1024];

// W_mB[i] = sum_c W_m[i,c] * BT[c]
__global__ void prep_wmb(const float* __restrict__ Wm, const float* __restrict__ BT) {
    int row  = blockIdx.x * 4 + (threadIdx.x >> 6);
    int lane = threadIdx.x & 63;
    float s = 0.f;
    for (int c = lane; c < 512; c += 64) s += Wm[row * 512 + c] * BT[c];
    for (int o = 32; o; o >>= 1) s += __shfl_down(s, o);
    if (lane == 0) g_WmB[row] = s;
}

// W_mA = W_m @ (I + AT)
__global__ void prep_wma(const float* __restrict__ Wm, const float* __restrict__ AT) {
    __shared__ float As[32][33], Bs[32][33];
    int d0 = blockIdx.x * 32, i0 = blockIdx.y * 32;
    int tx = threadIdx.x & 31, ty = threadIdx.x >> 5;
    float acc[4];
#pragma unroll
    for (int r = 0; r < 4; ++r) acc[r] = Wm[(i0 + ty + 8 * r) * 512 + d0 + tx];
    for (int c0 = 0; c0 < 512; c0 += 32) {
#pragma unroll
        for (int r = 0; r < 4; ++r) {
            As[ty + 8 * r][tx] = Wm[(i0 + ty + 8 * r) * 512 + c0 + tx];
            Bs[ty + 8 * r][tx] = AT[(c0 + ty + 8 * r) * 512 + d0 + tx];
        }
        __syncthreads();
#pragma unroll
        for (int c = 0; c < 32; ++c)
#pragma unroll
            for (int r = 0; r < 4; ++r) acc[r] += As[ty + 8 * r][c] * Bs[c][tx];
        __syncthreads();
    }
#pragma unroll
    for (int r = 0; r < 4; ++r) g_WmA[(i0 + ty + 8 * r) * 512 + d0 + tx] = acc[r];
}

// Build W_full, f16 hi/lo (lo x2048), in slice-major fragment order:
// storage s = (((sl*48 + kt)*3 + nt)*64 + lane)*8 + j
//   n = sl*48 + nt*16 + (lane&15),  k = kt*32 + ((lane>>4)&3)*8 + j
__global__ void prep_wfull(const float* __restrict__ Wh, const float* __restrict__ AT,
                           const float* __restrict__ BT, const float* __restrict__ eh,
                           const float* __restrict__ em, const float* __restrict__ ex,
                           const float* __restrict__ Wx) {
    int s = blockIdx.x * 256 + threadIdx.x;     // [0, 1536*1536)
    int j8 = s & 7;
    int u = s >> 3;
    int lane = u & 63;
    u >>= 6;                                    // [0, 4608)
    int nt = u % 3; u /= 3;
    int kt = u % 48;
    int sl = u / 48;
    int n = sl * 48 + nt * 16 + (lane & 15);
    int k = kt * 32 + ((lane >> 4) & 3) * 8 + j8;

    float w;
    if (n < 1024) {
        if (k < 1024) w = Wh[n * 1024 + k] + g_WmB[n] * eh[k];
        else          w = g_WmA[n * 512 + (k - 1024)] + g_WmB[n] * em[k - 1024];
    } else {
        int c = n - 1024;
        if (k < 1024) w = BT[c] * eh[k];
        else {
            int d = k - 1024;
            w = ((c == d) ? 1.f : 0.f) + AT[c * 512 + d] + BT[c] * em[d];
        }
    }
    _Float16 hi = (_Float16)w;
    g_Whi[s] = hi;
    g_Wlo[s] = (_Float16)((w - (float)hi) * LO_SCALE);

    if (s < NSTATE) {
        float b = (s < 1024) ? (Wx[s] + ex[0] * g_WmB[s]) : (BT[s - 1024] * ex[0]);
        g_wb[s] = b;
    }
    if (s < 2 * BATCH * NSTATE) { g_Shi[s] = (_Float16)0.f; g_Slo[s] = (_Float16)0.f; }
    if (s < 1024) g_bar[s] = 0u;
}

__launch_bounds__(256, 1)
__global__ void lmu_persist(const float* __restrict__ inputs) {
    __shared__ half8  lwh[SLICE_H8];            // 147456 B: W_hi slice
    __shared__ float4 red[4 * 3 * 64];          // 12288 B: K-split partials
    __shared__ int    s_sl;

    const int tid = threadIdx.x;

    // ---- physical XCD id + rank registration (island = XCD) ----
    unsigned xcd;
    asm volatile("s_getreg_b32 %0, hwreg(HW_REG_XCC_ID)" : "=s"(xcd));
    xcd &= 7u;
    if (tid == 0) {
        unsigned rank = __hip_atomic_fetch_add(g_bar + 512 + xcd * 64, 1u,
                                               __ATOMIC_RELAXED,
                                               __HIP_MEMORY_SCOPE_AGENT);
        s_sl = (int)(rank & 31u);               // column slice [0,32)
    }
    __syncthreads();
    const int isl = (int)xcd;                   // batch rows isl*16..+16
    const int sl  = s_sl;                       // cols sl*48..+48

    // stage W_hi slice -> LDS
    {
        const half8* src = (const half8*)g_Whi + (size_t)sl * SLICE_H8;
        for (int i = tid; i < SLICE_H8; i += 256) lwh[i] = src[i];
    }

    const int lane = tid & 63, wv = tid >> 6;
    const int quad = lane >> 4, l16 = lane & 15;
    const int kt0 = wv * 12;                    // this wave's K range
    const int rowA = isl * 16 + l16;            // A-frag batch row
    const half8* wlo = (const half8*)g_Wlo + (size_t)sl * SLICE_H8;
    unsigned* cnt = g_bar + isl * 64;           // island arrival counter

    // epilogue constants (wave wv<3 handles nt=wv)
    const int ncol = sl * 48 + wv * 16 + l16;
    const float wbv = (wv < 3) ? g_wb[ncol] : 0.f;
    const bool do_tanh = (sl * 48 + wv * 16) < 1024;

    // ---- W_lo ktiles 0..KREG-1 of this wave: REGISTER-resident, loaded once
    half8 wr[KREG * 3];                         // 24 x half8 = 96 VGPRs
#pragma unroll
    for (int ki = 0; ki < KREG; ++ki)
#pragma unroll
        for (int nt = 0; nt < 3; ++nt)
            wr[ki * 3 + nt] = wlo[((kt0 + ki) * 3 + nt) * 64 + lane];

    __syncthreads();

    int buf = 0;
    for (int t = 0; t < TSTEPS; ++t) {
        // PLAIN loads: producers share this XCD's L2 -> L2-local traffic
        const _Float16* shr =
            g_Shi + buf * BATCH * NSTATE + rowA * NSTATE + quad * 8;
        const _Float16* slr =
            g_Slo + buf * BATCH * NSTATE + rowA * NSTATE + quad * 8;

        floatx4 aA[3], aB[3], aC[3];
#pragma unroll
        for (int q = 0; q < 3; ++q) { aA[q] = (floatx4)0.f; aB[q] = (floatx4)0.f; aC[q] = (floatx4)0.f; }

        // ki 0..7: W_lo from registers
#pragma unroll
        for (int ki = 0; ki < KREG; ++ki) {
            const int kt = kt0 + ki;
            half8 ah = *(const half8*)(shr + kt * 32);
            half8 al = *(const half8*)(slr + kt * 32);
#pragma unroll
            for (int nt = 0; nt < 3; ++nt) {
                half8 bh = lwh[(kt * 3 + nt) * 64 + lane];
                aA[nt] = __builtin_amdgcn_mfma_f32_16x16x32_f16(ah, bh, aA[nt], 0, 0, 0);
                aB[nt] = __builtin_amdgcn_mfma_f32_16x16x32_f16(al, bh, aB[nt], 0, 0, 0);
                aC[nt] = __builtin_amdgcn_mfma_f32_16x16x32_f16(ah, wr[ki * 3 + nt], aC[nt], 0, 0, 0);
            }
        }
        // ki 8..11: W_lo streamed (49 KB/WG -> 1.57 MB/XCD, L2-resident)
#pragma unroll
        for (int ki = KREG; ki < 12; ++ki) {
            const int kt = kt0 + ki;
            half8 ah = *(const half8*)(shr + kt * 32);
            half8 al = *(const half8*)(slr + kt * 32);
#pragma unroll
            for (int nt = 0; nt < 3; ++nt) {
                half8 bh = lwh[(kt * 3 + nt) * 64 + lane];
                half8 bl = wlo[(kt * 3 + nt) * 64 + lane];
                aA[nt] = __builtin_amdgcn_mfma_f32_16x16x32_f16(ah, bh, aA[nt], 0, 0, 0);
                aB[nt] = __builtin_amdgcn_mfma_f32_16x16x32_f16(al, bh, aB[nt], 0, 0, 0);
                aC[nt] = __builtin_amdgcn_mfma_f32_16x16x32_f16(ah, bl, aC[nt], 0, 0, 0);
            }
        }

        // K-split partials -> LDS
#pragma unroll
        for (int nt = 0; nt < 3; ++nt) {
            floatx4 P = aA[nt] + (aB[nt] + aC[nt]) * LO_INV;
            red[(wv * 3 + nt) * 64 + lane] = float4{P[0], P[1], P[2], P[3]};
        }
        __syncthreads();

        // waves 0-2: reduce + bias + activation + hi/lo split + PLAIN store
        const int nbuf = buf ^ 1;
        if (wv < 3) {
            float4 v0 = red[(0 * 3 + wv) * 64 + lane];
            float4 v1 = red[(1 * 3 + wv) * 64 + lane];
            float4 v2 = red[(2 * 3 + wv) * 64 + lane];
            float4 v3 = red[(3 * 3 + wv) * 64 + lane];
            float vr[4] = {v0.x + v1.x + v2.x + v3.x, v0.y + v1.y + v2.y + v3.y,
                           v0.z + v1.z + v2.z + v3.z, v0.w + v1.w + v2.w + v3.w};
            _Float16* dh = g_Shi + nbuf * BATCH * NSTATE;
            _Float16* dl = g_Slo + nbuf * BATCH * NSTATE;
            const float* xt = inputs + t * BATCH + isl * 16 + quad * 4;
#pragma unroll
            for (int r = 0; r < 4; ++r) {
                int b = isl * 16 + quad * 4 + r;
                float v = vr[r] + xt[r] * wbv;
                if (do_tanh) v = tanhf(v);
                _Float16 hi = (_Float16)v;
                dh[b * NSTATE + ncol] = hi;
                dl[b * NSTATE + ncol] = (_Float16)((v - (float)hi) * LO_SCALE);
            }
        }

        // drain stores (syncthreads emits vmcnt(0)), then island barrier
        __builtin_amdgcn_fence(__ATOMIC_RELEASE, "workgroup");
        __syncthreads();
        if (tid == 0) {
            __hip_atomic_fetch_add(cnt, 1u, __ATOMIC_RELAXED,
                                   __HIP_MEMORY_SCOPE_AGENT);
            const unsigned target = (unsigned)ISL_WGS * (unsigned)(t + 1);
            int spin = 0;
            while (__hip_atomic_load(cnt, __ATOMIC_RELAXED,
                                     __HIP_MEMORY_SCOPE_AGENT) < target) {
                __builtin_amdgcn_s_sleep(1);
                if (++spin > (1 << 17)) break;  // deadman: no hang
            }
        }
        __syncthreads();
        // CU-local L1 invalidate only (L2 holds the island's fresh state)
        asm volatile("buffer_inv\n\ts_waitcnt vmcnt(0)" ::: "memory");
        __builtin_amdgcn_fence(__ATOMIC_ACQUIRE, "workgroup");
        buf = nbuf;
    }
}

// logits + softmax: one WG per batch row (final state in plane 0: 784 even;
// dispatch boundary flushes every XCD's L2 so state is globally visible).
__global__ void lmu_out(const float* __restrict__ Wd, const float* __restrict__ bd,
                        float* __restrict__ out) {
    __shared__ float red[272];
    int b = blockIdx.x;
    const _Float16* sh = g_Shi + b * NSTATE;
    const _Float16* sl = g_Slo + b * NSTATE;
    int tid = threadIdx.x;
    int c = tid & 15, chunk = tid >> 4;
    float part = 0.f;
    if (c < 10) {
        for (int i = chunk * 64; i < chunk * 64 + 64; ++i)
            part += ((float)sh[i] + (float)sl[i] * LO_INV) * Wd[c * 1024 + i];
    }
    red[chunk * 16 + c] = part;
    __syncthreads();
    if (tid < 10) {
        float lg = bd[tid];
        for (int q = 0; q < 16; ++q) lg += red[q * 16 + tid];
        red[256 + tid] = lg;
    }
    __syncthreads();
    if (tid < 10) {
        float mx = red[256];
        for (int q = 1; q < 10; ++q) mx = fmaxf(mx, red[256 + q]);
        float sm = 0.f;
        for (int q = 0; q < 10; ++q) sm += expf(red[256 + q] - mx);
        out[b * 10 + tid] = expf(red[256 + tid] - mx) / sm;
    }
}

extern "C" void kernel_launch(void* const* d_in, const int* in_sizes, int n_in,
                              void* d_out, int out_size, void* d_ws, size_t ws_size,
                              hipStream_t stream) {
    const float* inputs = (const float*)d_in[0];
    const float* e_x    = (const float*)d_in[1];
    const float* e_h    = (const float*)d_in[2];
    const float* e_m    = (const float*)d_in[3];
    const float* W_x    = (const float*)d_in[4];
    const float* W_h    = (const float*)d_in[5];
    const float* W_m    = (const float*)d_in[6];
    const float* AT     = (const float*)d_in[7];
    const float* BT     = (const float*)d_in[8];
    const float* W_d    = (const float*)d_in[9];
    const float* b_d    = (const float*)d_in[10];
    (void)d_ws; (void)ws_size; (void)in_sizes; (void)n_in;

    prep_wmb<<<256, 256, 0, stream>>>(W_m, BT);
    prep_wma<<<dim3(16, 32), 256, 0, stream>>>(W_m, AT);
    prep_wfull<<<9216, 256, 0, stream>>>(W_h, AT, BT, e_h, e_m, e_x, W_x);

    lmu_persist<<<256, 256, 0, stream>>>(inputs);

    lmu_out<<<128, 256, 0, stream>>>(W_d, b_d, (float*)d_out);
}

// Round 13
// 3953.016 us; speedup vs baseline: 4.2728x; 1.3616x over previous
//
#include <hip/hip_runtime.h>
#include <hip/hip_fp16.h>
#include <cmath>

// ---------------------------------------------------------------------------
// LMU fused recurrence.  One 128x1536 @ 1536x1536 GEMM per step (tanh on
// first 1024 cols, linear on last 512), x-dependent rank-1 bias.
// r13 = r12 with a compiler-proof barrier poll.
//   r12 failure RCA: poll used __hip_atomic_fetch_add(cnt, 0) -- LLVM
//   InstCombine canonicalizes RMW(+0) to an atomic LOAD, which at workgroup
//   scope is served (stale) from the CU L1 -> counter never advanced ->
//   deadman breaks -> island desync -> absmax 0.14.  Arrivals (+1) were fine.
//   Fix: poll is inline-asm  global_atomic_add vdst, vaddr, 0, off sc0
//   (+ s_waitcnt vmcnt(0)) -- a forced L2 RMW the compiler cannot elide.
// Design (unchanged from r12):
//   - XCD-local islands (s_getreg XCC_ID + rank registration, 1 WG/CU).
//   - Barrier atomics at WORKGROUP scope: RMWs execute in the local XCD L2
//     (~200cyc) instead of agent/LLC (~600cyc).  Busy spin, no s_sleep.
//   - W_lo fully register-resident: 36 x half8 = 144 AGPRs/lane (gfx950
//     unified file; r11 proved AGPR residency: VGPR_Count stayed 132).
//   - Plain L2-local state loads/stores; per-step CU-local L1 buffer_inv.
// Precision: EXACT r3-r11 verified scheme (absmax 4.9e-4): f16 hi/lo state
// and weights (lo x2048), fp32 MFMA accumulate, 3 products.
// ---------------------------------------------------------------------------

typedef _Float16 half8 __attribute__((ext_vector_type(8)));
typedef float floatx4 __attribute__((ext_vector_type(4)));

#define NSTATE   1536
#define BATCH    128
#define TSTEPS   784
#define KTILES   48
#define ISL_WGS  32                  // WGs per island (= CUs per XCD)
#define SLICE_H8 9216                // half8 per 48-col weight slice (48*3*64)
#define LO_SCALE 2048.0f
#define LO_INV   (1.0f / 2048.0f)

__device__ __align__(16) _Float16 g_Whi[NSTATE * NSTATE];
__device__ __align__(16) _Float16 g_Wlo[NSTATE * NSTATE];
__device__ float    g_wb[NSTATE];
__device__ float    g_WmA[1024 * 512];
__device__ float    g_WmB[1024];
__device__ __align__(16) _Float16 g_Shi[2 * BATCH * NSTATE];
__device__ __align__(16) _Float16 g_Slo[2 * BATCH * NSTATE];
// [xcd*64]: island arrival counters; [512 + xcd*64]: registration counters
__device__ unsigned g_bar[1024];

// Forced L2 atomic RMW poll (returns current counter value).  InstCombine
// cannot turn this into a cached load.
__device__ __forceinline__ unsigned poll_rmw(unsigned* p) {
    unsigned old;
    asm volatile("global_atomic_add %0, %1, %2, off sc0\n\ts_waitcnt vmcnt(0)"
                 : "=&v"(old)
                 : "v"(p), "v"(0u)
                 : "memory");
    return old;
}

// W_mB[i] = sum_c W_m[i,c] * BT[c]
__global__ void prep_wmb(const float* __restrict__ Wm, const float* __restrict__ BT) {
    int row  = blockIdx.x * 4 + (threadIdx.x >> 6);
    int lane = threadIdx.x & 63;
    float s = 0.f;
    for (int c = lane; c < 512; c += 64) s += Wm[row * 512 + c] * BT[c];
    for (int o = 32; o; o >>= 1) s += __shfl_down(s, o);
    if (lane == 0) g_WmB[row] = s;
}

// W_mA = W_m @ (I + AT)
__global__ void prep_wma(const float* __restrict__ Wm, const float* __restrict__ AT) {
    __shared__ float As[32][33], Bs[32][33];
    int d0 = blockIdx.x * 32, i0 = blockIdx.y * 32;
    int tx = threadIdx.x & 31, ty = threadIdx.x >> 5;
    float acc[4];
#pragma unroll
    for (int r = 0; r < 4; ++r) acc[r] = Wm[(i0 + ty + 8 * r) * 512 + d0 + tx];
    for (int c0 = 0; c0 < 512; c0 += 32) {
#pragma unroll
        for (int r = 0; r < 4; ++r) {
            As[ty + 8 * r][tx] = Wm[(i0 + ty + 8 * r) * 512 + c0 + tx];
            Bs[ty + 8 * r][tx] = AT[(c0 + ty + 8 * r) * 512 + d0 + tx];
        }
        __syncthreads();
#pragma unroll
        for (int c = 0; c < 32; ++c)
#pragma unroll
            for (int r = 0; r < 4; ++r) acc[r] += As[ty + 8 * r][c] * Bs[c][tx];
        __syncthreads();
    }
#pragma unroll
    for (int r = 0; r < 4; ++r) g_WmA[(i0 + ty + 8 * r) * 512 + d0 + tx] = acc[r];
}

// Build W_full, f16 hi/lo (lo x2048), in slice-major fragment order:
// storage s = (((sl*48 + kt)*3 + nt)*64 + lane)*8 + j
//   n = sl*48 + nt*16 + (lane&15),  k = kt*32 + ((lane>>4)&3)*8 + j
__global__ void prep_wfull(const float* __restrict__ Wh, const float* __restrict__ AT,
                           const float* __restrict__ BT, const float* __restrict__ eh,
                           const float* __restrict__ em, const float* __restrict__ ex,
                           const float* __restrict__ Wx) {
    int s = blockIdx.x * 256 + threadIdx.x;     // [0, 1536*1536)
    int j8 = s & 7;
    int u = s >> 3;
    int lane = u & 63;
    u >>= 6;                                    // [0, 4608)
    int nt = u % 3; u /= 3;
    int kt = u % 48;
    int sl = u / 48;
    int n = sl * 48 + nt * 16 + (lane & 15);
    int k = kt * 32 + ((lane >> 4) & 3) * 8 + j8;

    float w;
    if (n < 1024) {
        if (k < 1024) w = Wh[n * 1024 + k] + g_WmB[n] * eh[k];
        else          w = g_WmA[n * 512 + (k - 1024)] + g_WmB[n] * em[k - 1024];
    } else {
        int c = n - 1024;
        if (k < 1024) w = BT[c] * eh[k];
        else {
            int d = k - 1024;
            w = ((c == d) ? 1.f : 0.f) + AT[c * 512 + d] + BT[c] * em[d];
        }
    }
    _Float16 hi = (_Float16)w;
    g_Whi[s] = hi;
    g_Wlo[s] = (_Float16)((w - (float)hi) * LO_SCALE);

    if (s < NSTATE) {
        float b = (s < 1024) ? (Wx[s] + ex[0] * g_WmB[s]) : (BT[s - 1024] * ex[0]);
        g_wb[s] = b;
    }
    if (s < 2 * BATCH * NSTATE) { g_Shi[s] = (_Float16)0.f; g_Slo[s] = (_Float16)0.f; }
    if (s < 1024) g_bar[s] = 0u;
}

__launch_bounds__(256, 1)
__global__ void lmu_persist(const float* __restrict__ inputs) {
    __shared__ half8  lwh[SLICE_H8];            // 147456 B: W_hi slice
    __shared__ float4 red[4 * 3 * 64];          // 12288 B: K-split partials
    __shared__ int    s_sl;

    const int tid = threadIdx.x;

    // ---- physical XCD id + rank registration (island = XCD) ----
    unsigned xcd;
    asm volatile("s_getreg_b32 %0, hwreg(HW_REG_XCC_ID)" : "=s"(xcd));
    xcd &= 7u;
    if (tid == 0) {
        // genuine RMW (+1): lowered to global_atomic_add in the local L2
        unsigned rank = __hip_atomic_fetch_add(g_bar + 512 + xcd * 64, 1u,
                                               __ATOMIC_RELAXED,
                                               __HIP_MEMORY_SCOPE_WORKGROUP);
        s_sl = (int)(rank & 31u);               // column slice [0,32)
    }
    __syncthreads();
    const int isl = (int)xcd;                   // batch rows isl*16..+16
    const int sl  = s_sl;                       // cols sl*48..+48

    // stage W_hi slice -> LDS
    {
        const half8* src = (const half8*)g_Whi + (size_t)sl * SLICE_H8;
        for (int i = tid; i < SLICE_H8; i += 256) lwh[i] = src[i];
    }

    const int lane = tid & 63, wv = tid >> 6;
    const int quad = lane >> 4, l16 = lane & 15;
    const int kt0 = wv * 12;                    // this wave's K range
    const int rowA = isl * 16 + l16;            // A-frag batch row
    unsigned* cnt = g_bar + isl * 64;           // island arrival counter (local L2)

    // epilogue constants (wave wv<3 handles nt=wv)
    const int ncol = sl * 48 + wv * 16 + l16;
    const float wbv = (wv < 3) ? g_wb[ncol] : 0.f;
    const bool do_tanh = (sl * 48 + wv * 16) < 1024;

    // ---- W_lo: FULLY register-resident (36 x half8 = 144 AGPRs), loaded once
    half8 wr[12 * 3];
    {
        const half8* wlo = (const half8*)g_Wlo + (size_t)sl * SLICE_H8;
#pragma unroll
        for (int ki = 0; ki < 12; ++ki)
#pragma unroll
            for (int nt = 0; nt < 3; ++nt)
                wr[ki * 3 + nt] = wlo[((kt0 + ki) * 3 + nt) * 64 + lane];
    }

    __syncthreads();

    int buf = 0;
    for (int t = 0; t < TSTEPS; ++t) {
        // PLAIN loads: producers share this XCD's L2 -> L2-local traffic
        const _Float16* shr =
            g_Shi + buf * BATCH * NSTATE + rowA * NSTATE + quad * 8;
        const _Float16* slr =
            g_Slo + buf * BATCH * NSTATE + rowA * NSTATE + quad * 8;

        floatx4 aA[3], aB[3], aC[3];
#pragma unroll
        for (int q = 0; q < 3; ++q) { aA[q] = (floatx4)0.f; aB[q] = (floatx4)0.f; aC[q] = (floatx4)0.f; }

#pragma unroll
        for (int ki = 0; ki < 12; ++ki) {
            const int kt = kt0 + ki;
            half8 ah = *(const half8*)(shr + kt * 32);
            half8 al = *(const half8*)(slr + kt * 32);
#pragma unroll
            for (int nt = 0; nt < 3; ++nt) {
                half8 bh = lwh[(kt * 3 + nt) * 64 + lane];
                aA[nt] = __builtin_amdgcn_mfma_f32_16x16x32_f16(ah, bh, aA[nt], 0, 0, 0);
                aB[nt] = __builtin_amdgcn_mfma_f32_16x16x32_f16(al, bh, aB[nt], 0, 0, 0);
                aC[nt] = __builtin_amdgcn_mfma_f32_16x16x32_f16(ah, wr[ki * 3 + nt], aC[nt], 0, 0, 0);
            }
        }

        // K-split partials -> LDS
#pragma unroll
        for (int nt = 0; nt < 3; ++nt) {
            floatx4 P = aA[nt] + (aB[nt] + aC[nt]) * LO_INV;
            red[(wv * 3 + nt) * 64 + lane] = float4{P[0], P[1], P[2], P[3]};
        }
        __syncthreads();

        // waves 0-2: reduce + bias + activation + hi/lo split + PLAIN store
        const int nbuf = buf ^ 1;
        if (wv < 3) {
            float4 v0 = red[(0 * 3 + wv) * 64 + lane];
            float4 v1 = red[(1 * 3 + wv) * 64 + lane];
            float4 v2 = red[(2 * 3 + wv) * 64 + lane];
            float4 v3 = red[(3 * 3 + wv) * 64 + lane];
            float vr4[4] = {v0.x + v1.x + v2.x + v3.x, v0.y + v1.y + v2.y + v3.y,
                            v0.z + v1.z + v2.z + v3.z, v0.w + v1.w + v2.w + v3.w};
            _Float16* dh = g_Shi + nbuf * BATCH * NSTATE;
            _Float16* dl = g_Slo + nbuf * BATCH * NSTATE;
            const float* xt = inputs + t * BATCH + isl * 16 + quad * 4;
#pragma unroll
            for (int r = 0; r < 4; ++r) {
                int b = isl * 16 + quad * 4 + r;
                float v = vr4[r] + xt[r] * wbv;
                if (do_tanh) v = tanhf(v);
                _Float16 hi = (_Float16)v;
                dh[b * NSTATE + ncol] = hi;
                dl[b * NSTATE + ncol] = (_Float16)((v - (float)hi) * LO_SCALE);
            }
        }

        // drain stores (syncthreads emits vmcnt(0)), then LOCAL-L2 barrier:
        // arrival = wg-scope RMW(+1); poll = asm RMW(+0) sc0 (compiler-proof)
        __builtin_amdgcn_fence(__ATOMIC_RELEASE, "workgroup");
        __syncthreads();
        if (tid == 0) {
            __hip_atomic_fetch_add(cnt, 1u, __ATOMIC_RELAXED,
                                   __HIP_MEMORY_SCOPE_WORKGROUP);
            const unsigned target = (unsigned)ISL_WGS * (unsigned)(t + 1);
            int spin = 0;
            while (poll_rmw(cnt) < target) {
                if (++spin > (1 << 18)) break;  // deadman: no hang
            }
        }
        __syncthreads();
        // CU-local L1 invalidate only (L2 holds the island's fresh state)
        asm volatile("buffer_inv\n\ts_waitcnt vmcnt(0)" ::: "memory");
        __builtin_amdgcn_fence(__ATOMIC_ACQUIRE, "workgroup");
        buf = nbuf;
    }
}

// logits + softmax: one WG per batch row (final state in plane 0: 784 even;
// dispatch boundary flushes every XCD's L2 so state is globally visible).
__global__ void lmu_out(const float* __restrict__ Wd, const float* __restrict__ bd,
                        float* __restrict__ out) {
    __shared__ float red[272];
    int b = blockIdx.x;
    const _Float16* sh = g_Shi + b * NSTATE;
    const _Float16* sl = g_Slo + b * NSTATE;
    int tid = threadIdx.x;
    int c = tid & 15, chunk = tid >> 4;
    float part = 0.f;
    if (c < 10) {
        for (int i = chunk * 64; i < chunk * 64 + 64; ++i)
            part += ((float)sh[i] + (float)sl[i] * LO_INV) * Wd[c * 1024 + i];
    }
    red[chunk * 16 + c] = part;
    __syncthreads();
    if (tid < 10) {
        float lg = bd[tid];
        for (int q = 0; q < 16; ++q) lg += red[q * 16 + tid];
        red[256 + tid] = lg;
    }
    __syncthreads();
    if (tid < 10) {
        float mx = red[256];
        for (int q = 1; q < 10; ++q) mx = fmaxf(mx, red[256 + q]);
        float sm = 0.f;
        for (int q = 0; q < 10; ++q) sm += expf(red[256 + q] - mx);
        out[b * 10 + tid] = expf(red[256 + tid] - mx) / sm;
    }
}

extern "C" void kernel_launch(void* const* d_in, const int* in_sizes, int n_in,
                              void* d_out, int out_size, void* d_ws, size_t ws_size,
                              hipStream_t stream) {
    const float* inputs = (const float*)d_in[0];
    const float* e_x    = (const float*)d_in[1];
    const float* e_h    = (const float*)d_in[2];
    const float* e_m    = (const float*)d_in[3];
    const float* W_x    = (const float*)d_in[4];
    const float* W_h    = (const float*)d_in[5];
    const float* W_m    = (const float*)d_in[6];
    const float* AT     = (const float*)d_in[7];
    const float* BT     = (const float*)d_in[8];
    const float* W_d    = (const float*)d_in[9];
    const float* b_d    = (const float*)d_in[10];
    (void)d_ws; (void)ws_size; (void)in_sizes; (void)n_in;

    prep_wmb<<<256, 256, 0, stream>>>(W_m, BT);
    prep_wma<<<dim3(16, 32), 256, 0, stream>>>(W_m, AT);
    prep_wfull<<<9216, 256, 0, stream>>>(W_h, AT, BT, e_h, e_m, e_x, W_x);

    lmu_persist<<<256, 256, 0, stream>>>(inputs);

    lmu_out<<<128, 256, 0, stream>>>(W_d, b_d, (float*)d_out);
}